// Round 2
// baseline (467.004 us; speedup 1.0000x reference)
//
#include <hip/hip_runtime.h>

typedef __attribute__((ext_vector_type(4))) float float4v;

// One window per 128-thread block, grid 8192. Single 16 KB LDS buffer staged
// via global_load_lds (16B), then barrier, then the proven two-pass compute.
// Occupancy: LDS 16 KB -> 10 blocks/CU; __launch_bounds__(128,5) forces
// VGPR<=102 -> 5 waves/SIMD -> 20 waves/CU (2x the old double-buffered kernel).
// Cross-block TLP hides the staging drain instead of an in-block double buffer.
// LDS chunk swizzle sw(c)=c^((c>>3)&7) is applied on the GLOBAL side (per-lane
// address) since global_load_lds's LDS destination is fixed wavebase + lane*16.
__global__ __launch_bounds__(128, 5) void cattn_kernel(
    const float* __restrict__ rr, const float* __restrict__ gg,
    const float* __restrict__ bb, const float* __restrict__ ii,
    const float* __restrict__ w0, const float* __restrict__ b0,
    const float* __restrict__ w1, const float* __restrict__ b1,
    const float* __restrict__ w2, const float* __restrict__ b2,
    const float* __restrict__ w3, const float* __restrict__ b3,
    float* __restrict__ out)
{
    __shared__ float sm[4096];               // one 16 KB window buffer
    float4v* SM4 = (float4v*)sm;

    const int t   = threadIdx.x;
    const int wvi = t >> 6;                  // wave 0/1
    const int l   = t & 63;
    const int c4g = l ^ ((l >> 3) & 7);      // global float4-chunk this lane fetches

    // compute-lane mapping
    const int vloc = l >> 5;
    const int v    = (wvi << 1) | vloc;      // variant 0..3
    const int tok  = (l >> 3) & 3;           // query token
    const int h    = l & 7;                  // head
    const int kvt  = (v == 3) ? 1 : (v + 1); // kv tensor: g,b,ir,g (K==V)

    const float* srcs[4] = { rr, gg, bb, ii };

    const int wid = blockIdx.x;              // window id 0..8191
    const int bi  = wid >> 10;
    const int rem = wid & 1023;
    const int y0  = (rem >> 5) << 1;
    const int x0  = (rem & 31) << 1;

    // ---- stage the window (4 tensors x 2x2 tokens = 16 KB) into LDS ----
    #pragma unroll
    for (int kk = 0; kk < 8; ++kk) {
        // tensor = kk>>1 (CT), dy = kk&1 (CT), dx = wvi (wave-uniform)
        const float* g = srcs[kk >> 1]
            + (((size_t)(bi * 64 + y0 + (kk & 1))) * 64 + (size_t)(x0 + wvi)) * 256
            + (size_t)(c4g << 2);
        float* ldst = sm + (((kk << 1) | wvi) << 8);
        __builtin_amdgcn_global_load_lds(
            (const __attribute__((address_space(1))) void*)g,
            (__attribute__((address_space(3))) void*)ldst,
            16, 0, 0);
    }
    __syncthreads();                         // drains vmcnt -> buffer ready

    // ---------- compute ----------
    const int qbase = v * 256 + tok * 64 + h * 8;
    const int kbase = kvt * 256 + h * 8;

    // q fragment (also the residual)
    float q[32];
    #pragma unroll
    for (int j = 0; j < 8; ++j) {
        float4v c = SM4[qbase + (j ^ h)];
        #pragma unroll
        for (int e = 0; e < 4; ++e) q[j * 4 + e] = c[e];
    }

    // pass 1: scores
    float s[4] = {0.f, 0.f, 0.f, 0.f};
    #pragma unroll
    for (int j = 0; j < 8; ++j) {
        #pragma unroll
        for (int tk = 0; tk < 4; ++tk) {
            float4v c = SM4[kbase + tk * 64 + (j ^ h)];
            s[tk] += q[j*4+0]*c[0] + q[j*4+1]*c[1] + q[j*4+2]*c[2] + q[j*4+3]*c[3];
        }
    }
    #pragma unroll
    for (int tk = 0; tk < 4; ++tk) s[tk] *= 0.17677669529663687f;  // 1/sqrt(32)

    // softmax over 4
    float mx = fmaxf(fmaxf(s[0], s[1]), fmaxf(s[2], s[3]));
    float p[4];
    #pragma unroll
    for (int tk = 0; tk < 4; ++tk) p[tk] = __expf(s[tk] - mx);
    const float inv = 1.f / (p[0] + p[1] + p[2] + p[3]);
    #pragma unroll
    for (int tk = 0; tk < 4; ++tk) p[tk] *= inv;

    // pass 2: o = residual(q) + P·V
    float o[32];
    #pragma unroll
    for (int c = 0; c < 32; ++c) o[c] = q[c];
    #pragma unroll
    for (int tk = 0; tk < 4; ++tk) {
        const float pj = p[tk];
        #pragma unroll
        for (int j = 0; j < 8; ++j) {
            float4v c = SM4[kbase + tk * 64 + (j ^ h)];
            #pragma unroll
            for (int e = 0; e < 4; ++e) o[j * 4 + e] += pj * c[e];
        }
    }

    // LayerNorm over 256 ch: reduce across the 8 head-lanes
    float sum = 0.f, sq = 0.f;
    #pragma unroll
    for (int c = 0; c < 32; ++c) { sum += o[c]; sq += o[c] * o[c]; }
    #pragma unroll
    for (int off = 1; off < 8; off <<= 1) {
        sum += __shfl_xor(sum, off, 64);
        sq  += __shfl_xor(sq,  off, 64);
    }
    const float mu  = sum * (1.f / 256.f);
    const float var = sq * (1.f / 256.f) - mu * mu;
    const float rs  = rsqrtf(var + 1e-5f);

    // LN params loaded per-thread (8 KB total, shared by all blocks -> L1/L2-hot)
    const float* lw = ((v & 2) ? ((v & 1) ? w3 : w2) : ((v & 1) ? w1 : w0)) + h * 32;
    const float* lb = ((v & 2) ? ((v & 1) ? b3 : b2) : ((v & 1) ? b1 : b0)) + h * 32;

    const int dy = tok >> 1, dx = tok & 1;
    const size_t obase =
        ((((size_t)(bi * 64 + y0 + dy)) * 64) + (size_t)(x0 + dx)) * 1024
        + (size_t)(v << 8) + (size_t)(h << 5);

    #pragma unroll
    for (int j = 0; j < 8; ++j) {
        float4v wv = *(const float4v*)(lw + j * 4);
        float4v bv = *(const float4v*)(lb + j * 4);
        float4v ov;
        #pragma unroll
        for (int e = 0; e < 4; ++e)
            ov[e] = (o[j * 4 + e] - mu) * rs * wv[e] + bv[e];
        *(float4v*)(out + obase + (size_t)(j * 4)) = ov;
    }
}

extern "C" void kernel_launch(void* const* d_in, const int* in_sizes, int n_in,
                              void* d_out, int out_size, void* d_ws, size_t ws_size,
                              hipStream_t stream) {
    (void)in_sizes; (void)n_in; (void)d_ws; (void)ws_size; (void)out_size;
    const float* rr = (const float*)d_in[0];
    const float* gg = (const float*)d_in[1];
    const float* bb = (const float*)d_in[2];
    const float* ii = (const float*)d_in[3];
    const float* w0 = (const float*)d_in[4];
    const float* b0 = (const float*)d_in[5];
    const float* w1 = (const float*)d_in[6];
    const float* b1 = (const float*)d_in[7];
    const float* w2 = (const float*)d_in[8];
    const float* b2 = (const float*)d_in[9];
    const float* w3 = (const float*)d_in[10];
    const float* b3 = (const float*)d_in[11];
    float* out = (float*)d_out;

    cattn_kernel<<<8192, 128, 0, stream>>>(rr, gg, bb, ii,
                                           w0, b0, w1, b1, w2, b2, w3, b3, out);
}

// Round 3
// 409.021 us; speedup vs baseline: 1.1418x; 1.1418x over previous
//
#include <hip/hip_runtime.h>

typedef __attribute__((ext_vector_type(4))) float float4v;

// 8192 blocks x 128 threads, one window per block, single 16 KB LDS stage via
// global_load_lds (16B lanes), then the proven two-pass compute.
// KEY CHANGE vs round 2: output stores are made FULL-CACHE-LINE. Each 8-lane
// head group transposes its 8x8 float4-chunk tile through the (now dead) LDS
// window buffer so that store instruction j writes chunks {j*8+h} = 128 B
// lane-contiguous per group (every 64-B line fully covered by one instruction).
// This targets the 5x write amplification (WRITE_SIZE 653 MB vs 134 MB payload)
// seen with 128-B-strided 16-B partial-line stores at high concurrency.
__global__ __launch_bounds__(128, 5) void cattn_kernel(
    const float* __restrict__ rr, const float* __restrict__ gg,
    const float* __restrict__ bb, const float* __restrict__ ii,
    const float* __restrict__ w0, const float* __restrict__ b0,
    const float* __restrict__ w1, const float* __restrict__ b1,
    const float* __restrict__ w2, const float* __restrict__ b2,
    const float* __restrict__ w3, const float* __restrict__ b3,
    float* __restrict__ out)
{
    __shared__ float sm[4096];               // 16 KB: staged window, later scratch
    float4v* SM4 = (float4v*)sm;

    const int t   = threadIdx.x;
    const int wvi = t >> 6;                  // wave 0/1
    const int l   = t & 63;
    const int c4g = l ^ ((l >> 3) & 7);      // swizzled global chunk for staging

    const int vloc = l >> 5;
    const int v    = (wvi << 1) | vloc;      // variant 0..3
    const int tok  = (l >> 3) & 3;           // query token 0..3
    const int h    = l & 7;                  // head 0..7
    const int grp  = l >> 3;                 // group within wave = vloc*4+tok
    const int kvt  = (v == 3) ? 1 : (v + 1); // kv tensor: g,b,ir,g (K==V)

    const float* srcs[4] = { rr, gg, bb, ii };

    const int wid = blockIdx.x;              // window id 0..8191
    const int bi  = wid >> 10;
    const int rem = wid & 1023;
    const int y0  = (rem >> 5) << 1;
    const int x0  = (rem & 31) << 1;

    // ---- stage the window (4 tensors x 2x2 tokens = 16 KB) into LDS ----
    #pragma unroll
    for (int kk = 0; kk < 8; ++kk) {
        const float* g = srcs[kk >> 1]
            + (((size_t)(bi * 64 + y0 + (kk & 1))) * 64 + (size_t)(x0 + wvi)) * 256
            + (size_t)(c4g << 2);
        float* ldst = sm + (((kk << 1) | wvi) << 8);
        __builtin_amdgcn_global_load_lds(
            (const __attribute__((address_space(1))) void*)g,
            (__attribute__((address_space(3))) void*)ldst,
            16, 0, 0);
    }
    __syncthreads();                         // drains vmcnt -> buffer ready

    // ---------- compute ----------
    const int qbase = v * 256 + tok * 64 + h * 8;
    const int kbase = kvt * 256 + h * 8;

    float q[32];
    #pragma unroll
    for (int j = 0; j < 8; ++j) {
        float4v c = SM4[qbase + (j ^ h)];
        #pragma unroll
        for (int e = 0; e < 4; ++e) q[j * 4 + e] = c[e];
    }

    // pass 1: scores
    float s[4] = {0.f, 0.f, 0.f, 0.f};
    #pragma unroll
    for (int j = 0; j < 8; ++j) {
        #pragma unroll
        for (int tk = 0; tk < 4; ++tk) {
            float4v c = SM4[kbase + tk * 64 + (j ^ h)];
            s[tk] += q[j*4+0]*c[0] + q[j*4+1]*c[1] + q[j*4+2]*c[2] + q[j*4+3]*c[3];
        }
    }
    #pragma unroll
    for (int tk = 0; tk < 4; ++tk) s[tk] *= 0.17677669529663687f;  // 1/sqrt(32)

    // softmax over 4
    float mx = fmaxf(fmaxf(s[0], s[1]), fmaxf(s[2], s[3]));
    float p[4];
    #pragma unroll
    for (int tk = 0; tk < 4; ++tk) p[tk] = __expf(s[tk] - mx);
    const float inv = 1.f / (p[0] + p[1] + p[2] + p[3]);
    #pragma unroll
    for (int tk = 0; tk < 4; ++tk) p[tk] *= inv;

    // pass 2: o = residual(q) + P·V
    float o[32];
    #pragma unroll
    for (int c = 0; c < 32; ++c) o[c] = q[c];
    #pragma unroll
    for (int tk = 0; tk < 4; ++tk) {
        const float pj = p[tk];
        #pragma unroll
        for (int j = 0; j < 8; ++j) {
            float4v c = SM4[kbase + tk * 64 + (j ^ h)];
            #pragma unroll
            for (int e = 0; e < 4; ++e) o[j * 4 + e] += pj * c[e];
        }
    }

    // LayerNorm stats over 256 ch: reduce across the 8 head-lanes of the group
    float sum = 0.f, sq = 0.f;
    #pragma unroll
    for (int c = 0; c < 32; ++c) { sum += o[c]; sq += o[c] * o[c]; }
    #pragma unroll
    for (int off = 1; off < 8; off <<= 1) {
        sum += __shfl_xor(sum, off, 64);
        sq  += __shfl_xor(sq,  off, 64);
    }
    const float mu  = sum * (1.f / 256.f);
    const float var = sq * (1.f / 256.f) - mu * mu;
    const float rs  = rsqrtf(var + 1e-5f);

    // ---- transpose o through LDS so stores are lane-contiguous ----
    __syncthreads();   // all waves done reading K/V from the buffer

    // write: group tile [h][slot = j^h]  (64 chunks = 1 KB per group)
    const int wbase = (wvi << 9) + (grp << 6);
    #pragma unroll
    for (int j = 0; j < 8; ++j) {
        float4v c;
        #pragma unroll
        for (int e = 0; e < 4; ++e) c[e] = o[j * 4 + e];
        SM4[wbase + (h << 3) + (j ^ h)] = c;
    }
    asm volatile("s_waitcnt lgkmcnt(0)" ::: "memory");   // wave-internal visibility
    __builtin_amdgcn_sched_barrier(0);

    // read transposed + LN affine + full-line store.
    // store j covers out chunks {j*8+h} -> 128 B contiguous per 8-lane group.
    const float* lwr = (v & 2) ? ((v & 1) ? w3 : w2) : ((v & 1) ? w1 : w0);
    const float* lbr = (v & 2) ? ((v & 1) ? b3 : b2) : ((v & 1) ? b1 : b0);

    const int dy = tok >> 1, dx = tok & 1;
    float* op = out
        + ((size_t)(bi * 64 + y0 + dy) * 64 + (size_t)(x0 + dx)) * 1024
        + (size_t)(v << 8);

    #pragma unroll
    for (int j = 0; j < 8; ++j) {
        // chunk written by lane j of this group, register h: channels j*32+h*4..+4
        float4v c  = SM4[wbase + (j << 3) + (h ^ j)];
        const int co = j * 32 + h * 4;       // channel offset within the 256-row
        float4v wv = *(const float4v*)(lwr + co);
        float4v bv = *(const float4v*)(lbr + co);
        float4v ov;
        #pragma unroll
        for (int e = 0; e < 4; ++e)
            ov[e] = (c[e] - mu) * rs * wv[e] + bv[e];
        *(float4v*)(op + co) = ov;
    }
}

extern "C" void kernel_launch(void* const* d_in, const int* in_sizes, int n_in,
                              void* d_out, int out_size, void* d_ws, size_t ws_size,
                              hipStream_t stream) {
    (void)in_sizes; (void)n_in; (void)d_ws; (void)ws_size; (void)out_size;
    const float* rr = (const float*)d_in[0];
    const float* gg = (const float*)d_in[1];
    const float* bb = (const float*)d_in[2];
    const float* ii = (const float*)d_in[3];
    const float* w0 = (const float*)d_in[4];
    const float* b0 = (const float*)d_in[5];
    const float* w1 = (const float*)d_in[6];
    const float* b1 = (const float*)d_in[7];
    const float* w2 = (const float*)d_in[8];
    const float* b2 = (const float*)d_in[9];
    const float* w3 = (const float*)d_in[10];
    const float* b3 = (const float*)d_in[11];
    float* out = (float*)d_out;

    cattn_kernel<<<8192, 128, 0, stream>>>(rr, gg, bb, ii,
                                           w0, b0, w1, b1, w2, b2, w3, b3, out);
}

// Round 4
// 252.776 us; speedup vs baseline: 1.8475x; 1.6181x over previous
//
#include <hip/hip_runtime.h>

typedef __attribute__((ext_vector_type(4))) float float4v;

#define NBLK 2048

// Persistent 2048 blocks x 128 threads, 4 windows each, double-buffered LDS
// staging via global_load_lds (16B) -- the round-0 structure with proven-clean
// HBM traffic (FETCH 66 MB / WRITE 131 MB). CHANGE vs round 0: the full-drain
// __syncthreads() (implicit vmcnt(0) -- which serialized the prefetch against
// compute) is replaced by counted s_waitcnt vmcnt(8) + raw s_barrier, so the
// next window's 8 LDS-DMA loads stay in flight across the barrier and overlap
// compute (T4). A second raw s_barrier after compute gives WAR protection for
// the buffer the next iteration overwrites. Epilogue stores are full-cache-line
// via an in-place transpose through the just-computed (dead) buffer half.
__global__ __launch_bounds__(128) void cattn_kernel(
    const float* __restrict__ rr, const float* __restrict__ gg,
    const float* __restrict__ bb, const float* __restrict__ ii,
    const float* __restrict__ w0, const float* __restrict__ b0,
    const float* __restrict__ w1, const float* __restrict__ b1,
    const float* __restrict__ w2, const float* __restrict__ b2,
    const float* __restrict__ w3, const float* __restrict__ b3,
    float* __restrict__ out)
{
    __shared__ float sm[2 * 4096];           // two 16 KB window buffers
    float4v* SM4 = (float4v*)sm;

    const int t   = threadIdx.x;
    const int wvi = t >> 6;                  // wave 0/1
    const int l   = t & 63;
    const int c4g = l ^ ((l >> 3) & 7);      // swizzled global chunk for staging

    // compute-lane mapping
    const int vloc = l >> 5;
    const int v    = (wvi << 1) | vloc;      // variant 0..3
    const int tok  = (l >> 3) & 3;           // query token 0..3
    const int h    = l & 7;                  // head 0..7
    const int grp  = l >> 3;                 // group within wave = vloc*4+tok
    const int kvt  = (v == 3) ? 1 : (v + 1); // kv tensor: g,b,ir,g (K==V)

    // hoisted LN params, TRANSPOSED indexing to match the full-line epilogue:
    // store j covers channels j*32 + h*4 .. +4  (VGPR cost is free: LDS is the
    // occupancy cap at 5 blocks/CU; 156 VGPR still allows 3 waves/SIMD)
    const float* lwr = (v & 2) ? ((v & 1) ? w3 : w2) : ((v & 1) ? w1 : w0);
    const float* lbr = (v & 2) ? ((v & 1) ? b3 : b2) : ((v & 1) ? b1 : b0);
    float4v wp[8], bp[8];
    #pragma unroll
    for (int j = 0; j < 8; ++j) {
        wp[j] = *(const float4v*)(lwr + j * 32 + h * 4);
        bp[j] = *(const float4v*)(lbr + j * 32 + h * 4);
    }

    const float* srcs[4] = { rr, gg, bb, ii };

    // async stage one window (16 KB) into LDS buffer `buf`: 8 loads per wave
    auto issue = [&](int buf, int wid) {
        const int bi  = wid >> 10;
        const int rem = wid & 1023;
        const int y0  = (rem >> 5) << 1;
        const int x0  = (rem & 31) << 1;
        #pragma unroll
        for (int kk = 0; kk < 8; ++kk) {
            // tensor = kk>>1 (CT), dy = kk&1 (CT), dx = wvi (wave-uniform)
            const float* g = srcs[kk >> 1]
                + (((size_t)(bi * 64 + y0 + (kk & 1))) * 64 + (size_t)(x0 + wvi)) * 256
                + (size_t)(c4g << 2);
            float* ldst = sm + buf * 4096 + (((kk << 1) | wvi) << 8);
            __builtin_amdgcn_global_load_lds(
                (const __attribute__((address_space(1))) void*)g,
                (__attribute__((address_space(3))) void*)ldst,
                16, 0, 0);
        }
    };

    int wid = blockIdx.x;                    // 4 windows: wid, +2048, +4096, +6144
    issue(0, wid);
    int cur = 0;

    #pragma unroll
    for (int it = 0; it < 4; ++it, wid += NBLK) {
        // prefetch next window, then wait ONLY for the current buffer's loads.
        // vmcnt ledger per wave (in-order retirement): the 8 just-issued loads
        // are the newest 8 ops, so vmcnt(8) retires everything older -- the
        // current buffer's loads and any outstanding epilogue stores.
        if (it < 3) {
            issue(cur ^ 1, wid + NBLK);
            asm volatile("s_waitcnt vmcnt(8)" ::: "memory");
        } else {
            asm volatile("s_waitcnt vmcnt(0)" ::: "memory");
        }
        __builtin_amdgcn_s_barrier();        // other wave's loads also done
        __builtin_amdgcn_sched_barrier(0);

        // ---------- compute window `wid` from buf[cur] ----------
        const int bi  = wid >> 10;
        const int rem = wid & 1023;
        const int y0  = (rem >> 5) << 1;
        const int x0  = (rem & 31) << 1;

        const int bb4   = cur << 10;                       // buf offset in chunks
        const int qbase = bb4 + v * 256 + tok * 64 + h * 8;
        const int kbase = bb4 + kvt * 256 + h * 8;

        // q fragment (also the residual)
        float q[32];
        #pragma unroll
        for (int j = 0; j < 8; ++j) {
            float4v c = SM4[qbase + (j ^ h)];
            #pragma unroll
            for (int e = 0; e < 4; ++e) q[j * 4 + e] = c[e];
        }

        // pass 1: scores
        float s[4] = {0.f, 0.f, 0.f, 0.f};
        #pragma unroll
        for (int j = 0; j < 8; ++j) {
            #pragma unroll
            for (int tk = 0; tk < 4; ++tk) {
                float4v c = SM4[kbase + tk * 64 + (j ^ h)];
                s[tk] += q[j*4+0]*c[0] + q[j*4+1]*c[1] + q[j*4+2]*c[2] + q[j*4+3]*c[3];
            }
        }
        #pragma unroll
        for (int tk = 0; tk < 4; ++tk) s[tk] *= 0.17677669529663687f;  // 1/sqrt(32)

        // softmax over 4
        float mx = fmaxf(fmaxf(s[0], s[1]), fmaxf(s[2], s[3]));
        float p[4];
        #pragma unroll
        for (int tk = 0; tk < 4; ++tk) p[tk] = __expf(s[tk] - mx);
        const float inv = 1.f / (p[0] + p[1] + p[2] + p[3]);
        #pragma unroll
        for (int tk = 0; tk < 4; ++tk) p[tk] *= inv;

        // pass 2: o = residual(q) + P·V
        float o[32];
        #pragma unroll
        for (int c = 0; c < 32; ++c) o[c] = q[c];
        #pragma unroll
        for (int tk = 0; tk < 4; ++tk) {
            const float pj = p[tk];
            #pragma unroll
            for (int j = 0; j < 8; ++j) {
                float4v c = SM4[kbase + tk * 64 + (j ^ h)];
                #pragma unroll
                for (int e = 0; e < 4; ++e) o[j * 4 + e] += pj * c[e];
            }
        }

        // LayerNorm stats over 256 ch: reduce across the 8 head-lanes
        float sum = 0.f, sq = 0.f;
        #pragma unroll
        for (int c = 0; c < 32; ++c) { sum += o[c]; sq += o[c] * o[c]; }
        #pragma unroll
        for (int off = 1; off < 8; off <<= 1) {
            sum += __shfl_xor(sum, off, 64);
            sq  += __shfl_xor(sq,  off, 64);
        }
        const float mu  = sum * (1.f / 256.f);
        const float var = sq * (1.f / 256.f) - mu * mu;
        const float rs  = rsqrtf(var + 1e-5f);

        // ---- full-line epilogue: transpose o through buf[cur] (now dead;
        //      each wave uses only its own half -> no extra barrier needed) ----
        const int wbase = bb4 + (wvi << 9) + (grp << 6);
        #pragma unroll
        for (int j = 0; j < 8; ++j) {
            float4v c;
            #pragma unroll
            for (int e = 0; e < 4; ++e) c[e] = o[j * 4 + e];
            SM4[wbase + (h << 3) + (j ^ h)] = c;
        }
        asm volatile("s_waitcnt lgkmcnt(0)" ::: "memory");
        __builtin_amdgcn_sched_barrier(0);

        const int dy = tok >> 1, dx = tok & 1;
        float* op = out
            + ((size_t)(bi * 64 + y0 + dy) * 64 + (size_t)(x0 + dx)) * 1024
            + (size_t)(v << 8);

        #pragma unroll
        for (int j = 0; j < 8; ++j) {
            // chunk written by lane j of this group, reg h: channels j*32+h*4..+4
            float4v c = SM4[wbase + (j << 3) + (h ^ j)];
            float4v ov;
            #pragma unroll
            for (int e = 0; e < 4; ++e)
                ov[e] = (c[e] - mu) * rs * wp[j][e] + bp[j][e];
            *(float4v*)(op + j * 32 + h * 4) = ov;
        }

        // WAR barrier: next iteration's issue() overwrites buf[cur]; every
        // wave's LDS reads (compute + transpose scratch) are complete here.
        if (it < 3) __builtin_amdgcn_s_barrier();
        cur ^= 1;
    }
}

extern "C" void kernel_launch(void* const* d_in, const int* in_sizes, int n_in,
                              void* d_out, int out_size, void* d_ws, size_t ws_size,
                              hipStream_t stream) {
    (void)in_sizes; (void)n_in; (void)d_ws; (void)ws_size; (void)out_size;
    const float* rr = (const float*)d_in[0];
    const float* gg = (const float*)d_in[1];
    const float* bb = (const float*)d_in[2];
    const float* ii = (const float*)d_in[3];
    const float* w0 = (const float*)d_in[4];
    const float* b0 = (const float*)d_in[5];
    const float* w1 = (const float*)d_in[6];
    const float* b1 = (const float*)d_in[7];
    const float* w2 = (const float*)d_in[8];
    const float* b2 = (const float*)d_in[9];
    const float* w3 = (const float*)d_in[10];
    const float* b3 = (const float*)d_in[11];
    float* out = (float*)d_out;

    cattn_kernel<<<NBLK, 128, 0, stream>>>(rr, gg, bb, ii,
                                           w0, b0, w1, b1, w2, b2, w3, b3, out);
}